// Round 1
// baseline (272.370 us; speedup 1.0000x reference)
//
#include <hip/hip_runtime.h>
#include <stdint.h>

typedef unsigned int   u32;
typedef unsigned short u16;
typedef __bf16 bf16x8 __attribute__((ext_vector_type(8)));
typedef float  f32x4  __attribute__((ext_vector_type(4)));

// ---------------------------------------------------------------------------
// Compile-time DWT analysis matrix Wd[84][64]:
//   coeffs = Wd @ x  for a length-64 signal, db4, mode='reflect', J=3.
// Row order: lo3 (14) | hi1 (35) | hi2 (21) | hi3 (14)  — matches reference
// concat [lo, hi1, hi2, hi3].  Identical arithmetic to the previous runtime
// builder (same tap order; skipping a +0.0f term is exact).
// ---------------------------------------------------------------------------
struct WdT { float v[84][64]; };

constexpr WdT build_wd() {
    WdT W{};
    const float GLc[8] = { 0.23037781330885523f,  0.7148465705525415f,
                           0.6308807679295904f,  -0.02798376941698385f,
                          -0.18703481171888114f,  0.030841381835986965f,
                           0.032883011666982945f,-0.010597401784997278f };
    const float GHc[8] = {-0.010597401784997278f,-0.032883011666982945f,
                           0.030841381835986965f, 0.18703481171888114f,
                          -0.02798376941698385f, -0.6308807679295904f,
                           0.7148465705525415f,  -0.23037781330885523f };
    for (int j = 0; j < 64; ++j) {
        float lo1[35] = {}, lo2[21] = {};
        for (int i = 0; i < 35; ++i) {            // level 1: N=64, reflect 6
            float sl = 0.f, sh = 0.f;
            for (int t = 0; t < 8; ++t) {
                int s = 2*i + t - 6;
                if (s < 0)   s = -s;
                if (s >= 64) s = 126 - s;
                if (s == j) { sl += GLc[t]; sh += GHc[t]; }
            }
            lo1[i] = sl; W.v[14 + i][j] = sh;
        }
        for (int i = 0; i < 21; ++i) {            // level 2: N=35 (+1 zero)
            float sl = 0.f, sh = 0.f;
            for (int t = 0; t < 8; ++t) {
                int s = 2*i + t - 6;
                if (s < 0)   s = -s;
                if (s >= 36) s = 70 - s;
                if (s < 35) { sl += lo1[s]*GLc[t]; sh += lo1[s]*GHc[t]; }
            }
            lo2[i] = sl; W.v[49 + i][j] = sh;
        }
        for (int i = 0; i < 14; ++i) {            // level 3: N=21 (+1 zero)
            float sl = 0.f, sh = 0.f;
            for (int t = 0; t < 8; ++t) {
                int s = 2*i + t - 6;
                if (s < 0)   s = -s;
                if (s >= 22) s = 42 - s;
                if (s < 21) { sl += lo2[s]*GLc[t]; sh += lo2[s]*GHc[t]; }
            }
            W.v[i][j] = sl; W.v[70 + i][j] = sh;
        }
    }
    return W;
}

__constant__ WdT WD = build_wd();

__device__ inline u16 f32_bf16(float f) {
    u32 u = __float_as_uint(f);
    u += 0x7fffu + ((u >> 16) & 1u);
    return (u16)(u >> 16);
}
__device__ inline u32 pack2_bf16(float a, float b) {
    u32 ua = __float_as_uint(a); ua += 0x7fffu + ((ua >> 16) & 1u);
    u32 ub = __float_as_uint(b); ub += 0x7fffu + ((ub >> 16) & 1u);
    return (ua >> 16) | (ub & 0xffff0000u);
}

// ---------------------------------------------------------------------------
// Kernel 1: fold conv weights with the constant DWT matrix, emitting bf16
// directly in MFMA B-fragment order:
//   Wf[(((s*8+nt)*128 + kb)*64 + lane)*8 + j]
//     = Wp[n = nt*16 + (lane&15)][i = kb*32 + (lane>>4)*8 + j]
// where Wp[n][i = t*64 + hw] = sum_tau cw[s,n,tau,hw] * Wd[tau][t].
// One block per (s,n). WD[tau][t0+j] is wave-uniform -> scalar K$ loads.
// No LDS, no barrier, no scratch.
// ---------------------------------------------------------------------------
__global__ __launch_bounds__(256) void fold_w(const float* __restrict__ cw,
                                              u16* __restrict__ Wf) {
    const int tid = threadIdx.x;
    const int sk  = blockIdx.x;                  // 0..511 = s*128 + n
    const int s   = sk >> 7;
    const int n   = sk & 127;
    const int hw  = tid & 63;
    const int tg  = __builtin_amdgcn_readfirstlane((int)(tid >> 6)); // 0..3
    const int t0  = tg * 16;
    const float* wk = cw + (size_t)sk * (84 * 64);

    float acc[16];
#pragma unroll
    for (int j = 0; j < 16; ++j) acc[j] = 0.f;

#pragma unroll 4
    for (int tau = 0; tau < 84; ++tau) {
        const float wv = wk[tau * 64 + hw];      // coalesced 256 B / wave
#pragma unroll
        for (int j = 0; j < 16; ++j) acc[j] += wv * WD.v[tau][t0 + j]; // s_load
    }

    // scatter into B-fragment layout
    const int nt  = n >> 4;
    const int fr  = n & 15;
    const int fq  = (hw >> 3) & 3;
    const int jj  = hw & 7;
    const int kbh = hw >> 5;                     // kb = t*2 + (hw>>5)
#pragma unroll
    for (int j = 0; j < 16; ++j) {
        const int t = t0 + j;
        const size_t idx =
            ((((size_t)(s * 8 + nt)) * 128 + t * 2 + kbh) * 64 + fq * 16 + fr) * 8 + jj;
        Wf[idx] = f32_bf16(acc[j]);
    }
}

// ---------------------------------------------------------------------------
// Kernel 2: fused MFMA GEMM + K-reduction + bias + leaky-ReLU.
// Grid 512 blocks = (s 0..3) x (mt 0..127); 8 waves/block.
// Wave w computes the 16(m) x 128(n) tile over K-slice [w*512,(w+1)*512),
// then all waves ds_add_f32 into one padded LDS tile; epilogue applies
// bias + leakyReLU and writes the final 16x128 output tile. No P partials,
// no third kernel.
// ---------------------------------------------------------------------------
__global__ __launch_bounds__(512, 4) void gemm_f(const float* __restrict__ X,
                                                 const u16* __restrict__ Wf,
                                                 const float* __restrict__ bias,
                                                 float* __restrict__ out) {
    __shared__ __align__(16) float R[16 * 132];  // +4 pad: 2-way banks = free
    const int tid  = threadIdx.x;
    const int lane = tid & 63;
    const int w    = tid >> 6;                   // K-slice 0..7
    const int s    = blockIdx.x >> 7;            // subwindow
    const int mt   = blockIdx.x & 127;           // m-tile (16 rows)
    const int fr   = lane & 15;
    const int fq   = lane >> 4;
    const int kb0  = w * 16;

    for (int i = tid; i < 16 * 132; i += 512) R[i] = 0.f;

    const float* xg = X + (size_t)(mt * 16 + fr) * 16384 + s * 4096 + kb0 * 32 + fq * 8;
    const u16*   wg = Wf + ((size_t)(s * 8) * 128 + kb0) * 512 + lane * 8;
    // strides (u16): nt -> 128*512 = 65536 ; kb -> 512

    f32x4 acc[8];
#pragma unroll
    for (int nt = 0; nt < 8; ++nt) acc[nt] = (f32x4){0.f, 0.f, 0.f, 0.f};

    // prefetch A for kb=0 (each lane: 32 B contiguous, fully coalesced)
    f32x4 a0 = __builtin_nontemporal_load(reinterpret_cast<const f32x4*>(xg));
    f32x4 a1 = __builtin_nontemporal_load(reinterpret_cast<const f32x4*>(xg) + 1);

    __syncthreads();                             // R zeroed before any ds_add

#pragma unroll 2
    for (int kb = 0; kb < 16; ++kb) {
        union { u32 u[4]; bf16x8 v; } av;
        av.u[0] = pack2_bf16(a0.x, a0.y); av.u[1] = pack2_bf16(a0.z, a0.w);
        av.u[2] = pack2_bf16(a1.x, a1.y); av.u[3] = pack2_bf16(a1.z, a1.w);
        const int kn = (kb + 1 < 16) ? kb + 1 : kb;   // clamped prefetch
        a0 = __builtin_nontemporal_load(reinterpret_cast<const f32x4*>(xg + (size_t)kn * 32));
        a1 = __builtin_nontemporal_load(reinterpret_cast<const f32x4*>(xg + (size_t)kn * 32) + 1);
        const u16* wb = wg + (size_t)kb * 512;
#pragma unroll
        for (int nt = 0; nt < 8; ++nt) {
            bf16x8 bf = *reinterpret_cast<const bf16x8*>(wb + (size_t)nt * 65536);
            acc[nt] = __builtin_amdgcn_mfma_f32_16x16x32_bf16(av.v, bf, acc[nt], 0, 0, 0);
        }
    }

    // in-block K reduction: acc[nt][r] -> row fq*4+r, col nt*16+fr
#pragma unroll
    for (int nt = 0; nt < 8; ++nt)
#pragma unroll
        for (int r = 0; r < 4; ++r)
            atomicAdd(&R[(fq * 4 + r) * 132 + nt * 16 + fr], acc[nt][r]);
    __syncthreads();

    // epilogue: 512 threads x 4 outputs = 16x128 tile
    {
        const int o   = tid * 4;                 // 0..2044
        const int row = o >> 7;
        const int col = o & 127;
        f32x4 v = *reinterpret_cast<const f32x4*>(&R[row * 132 + col]);
        const f32x4 b = *reinterpret_cast<const f32x4*>(bias + s * 128 + col);
        f32x4 u = v + b;
        u.x = u.x > 0.f ? u.x : 0.01f * u.x;
        u.y = u.y > 0.f ? u.y : 0.01f * u.y;
        u.z = u.z > 0.f ? u.z : 0.01f * u.z;
        u.w = u.w > 0.f ? u.w : 0.01f * u.w;
        __builtin_nontemporal_store(
            u, reinterpret_cast<f32x4*>(out + (size_t)(mt * 16 + row) * 512 + s * 128 + col));
    }
}

// ---------------------------------------------------------------------------
extern "C" void kernel_launch(void* const* d_in, const int* in_sizes, int n_in,
                              void* d_out, int out_size, void* d_ws, size_t ws_size,
                              hipStream_t stream) {
    const float* x  = (const float*)d_in[0];   // [2048,1,256,8,8] fp32
    const float* cw = (const float*)d_in[1];   // [4,128,84,8,8]   fp32
    const float* cb = (const float*)d_in[2];   // [4,128]          fp32
    float* out = (float*)d_out;                // [2048,512]       fp32

    u16* Wf = (u16*)d_ws;                      // 4 MiB, B-fragment order

    fold_w<<<512, 256, 0, stream>>>(cw, Wf);
    gemm_f<<<512, 512, 0, stream>>>(x, Wf, cb, out);
}